// Round 5
// baseline (428.317 us; speedup 1.0000x reference)
//
#include <hip/hip_runtime.h>
#include <stdint.h>

#define COUT 32

typedef __attribute__((address_space(3))) unsigned int as3u;
typedef __attribute__((address_space(1))) unsigned int as1u;

// Phase ph covers xs channels [ph*32,ph*32+32) = ys slot src, element index
// l = rb + di*Si + dj*Sj + dk*Sk (block-local di,dj,dk plus i0/j0/k0 offsets).
__device__ __forceinline__ void phase_params(int ph, int& src, int& Si, int& Sj, int& Sk,
                                             int& rb, int& cbf) {
  const int g = ph >> 2, q = ph & 3;
  const int neg = q & 1, v = q >> 1;
  src = (ph & ~3) | (neg << 1) | v;
  rb = neg ? 32767 : 0;
  const int sA = v ? 1 : 32, sB = v ? 32 : 1;
  if (g == 0)      { Si = 1024; Sj = sA; Sk = sB; }
  else if (g == 1) { Sj = 1024; Sk = sA; Si = sB; }
  else             { Sk = 1024; Si = sA; Sj = sB; }
  if (neg) { Si = -Si; Sj = -Sj; Sk = -Sk; }
  cbf = ((g == 1) && (v == 0)) || ((g == 2) && (v == 1));  // |Si|==1 (class B)
}

__device__ __forceinline__ int phase_cb(int ph) {
  const int g = ph >> 2, v = (ph >> 1) & 1;
  return ((g == 1) && (v == 0)) || ((g == 2) && (v == 1));
}

// Stage one phase's x-tile (32 ch x 512 pos, 64KB). 32 global_load_lds dword
// per wave; LDS dest lane-linear, permutation on the global address.
// Class A storage: stor = di*64 + dj*8 + dk  (instr pr = di; lane = dj*8+dk).
// Class B storage: stor = dk*64 + dj*8 + e, with di = e ^ dj
//   (instr pr = dk; lane = dj*8+e; XOR keeps each 8-run inside one 32B segment,
//    and makes compute-side b32 reads exactly 2 lanes/bank = free).
__device__ __forceinline__ void stage_phase(
    const float* __restrict__ ys, float* lbuf, int ph,
    int b, int i0, int j0, int k0, int wv, int lane)
{
  int s, Si, Sj, Sk, rb, cbf;
  phase_params(ph, s, Si, Sj, Sk, rb, cbf);
  const int lhi = lane >> 3, llo = lane & 7;
  const float* ybase = ys + (((size_t)((b*12 + s)*COUT + wv*4)) << 15);
  if (!cbf) {
    // lhi = dj, llo = dk; per-instr step = Si
    const int sc0 = rb + i0*Si + j0*Sj + k0*Sk + lhi*Sj + llo*Sk;
#pragma unroll
    for (int cc = 0; cc < 4; ++cc) {
#pragma unroll
      for (int pr = 0; pr < 8; ++pr) {
        const float* src = ybase + (((size_t)cc) << 15) + (sc0 + pr*Si);
        float* dst = lbuf + (wv*4 + cc)*512 + pr*64;
        __builtin_amdgcn_global_load_lds((const as1u*)src, (as3u*)dst, 4, 0, 0);
      }
    }
  } else {
    // lhi = dj, llo = e, di = e^dj; per-instr step = Sk (pr = dk)
    const int sc0 = rb + i0*Si + j0*Sj + k0*Sk + lhi*Sj + (llo ^ lhi)*Si;
#pragma unroll
    for (int cc = 0; cc < 4; ++cc) {
#pragma unroll
      for (int pr = 0; pr < 8; ++pr) {
        const float* src = ybase + (((size_t)cc) << 15) + (sc0 + pr*Sk);
        float* dst = lbuf + (wv*4 + cc)*512 + pr*64;
        __builtin_amdgcn_global_load_lds((const as1u*)src, (as3u*)dst, 4, 0, 0);
      }
    }
  }
}

// Per thread: O=8 output channels (o = og*8+oo), P=4 positions (dk = 4u+p).
// Weights come in via wave-uniform scalar loads (SGPRs, broadcast-free);
// x via ds_read_b128 (class A) or 4x ds_read_b32 immediate-offset (class B).
__device__ __forceinline__ void compute_phase(
    const float* __restrict__ wb, const float* lbuf, int classB,
    int storA, int storB, float acc[8][4])
{
#pragma unroll
  for (int c4 = 0; c4 < 8; ++c4) {
    float4 ws[8];
#pragma unroll
    for (int oo = 0; oo < 8; ++oo)
      ws[oo] = *(const float4*)(wb + oo*384 + c4*4);   // uniform -> s_load_dwordx4
    float4 xv[4];
    if (!classB) {
#pragma unroll
      for (int cc = 0; cc < 4; ++cc)
        xv[cc] = *(const float4*)(lbuf + (c4*4 + cc)*512 + storA);
    } else {
#pragma unroll
      for (int cc = 0; cc < 4; ++cc) {
        const float* bp = lbuf + (c4*4 + cc)*512 + storB;
        xv[cc].x = bp[0]; xv[cc].y = bp[64]; xv[cc].z = bp[128]; xv[cc].w = bp[192];
      }
    }
#pragma unroll
    for (int oo = 0; oo < 8; ++oo) {
#pragma unroll
      for (int cc = 0; cc < 4; ++cc) {
        const float wv_ = ((const float*)&ws[oo])[cc];
        acc[oo][0] = __builtin_fmaf(xv[cc].x, wv_, acc[oo][0]);
        acc[oo][1] = __builtin_fmaf(xv[cc].y, wv_, acc[oo][1]);
        acc[oo][2] = __builtin_fmaf(xv[cc].z, wv_, acc[oo][2]);
        acc[oo][3] = __builtin_fmaf(xv[cc].w, wv_, acc[oo][3]);
      }
    }
  }
}

__global__ __launch_bounds__(512, 2) void k_fused(
    const float* __restrict__ ys, const float* __restrict__ w,
    const float* __restrict__ cb, float* __restrict__ out,
    float* __restrict__ stats)
{
  __shared__ float lds[2][COUT*512];   // 2 x 64KB x-tile double buffer
  const int tid  = threadIdx.x;
  const int lane = tid & 63, wv = tid >> 6;
  const int bid  = blockIdx.x;
  const int b  = bid >> 6;
  const int i0 = ((bid >> 4) & 3) * 8;
  const int j0 = ((bid >> 2) & 3) * 8;
  const int k0 = (bid & 3) * 8;

  // thread tiling: og (wave-uniform) x (di,dj,u)
  const int og = __builtin_amdgcn_readfirstlane(tid >> 7);
  const int pg = tid & 127;
  const int di = pg >> 4, dj = (pg >> 1) & 7, u = pg & 1;

  const int storA = di*64 + dj*8 + 4*u;            // class A: b128 over 4 pos
  const int storB = 256*u + 8*dj + (di ^ dj);      // class B: +64*p per pos

  float acc[8][4];
#pragma unroll
  for (int oo = 0; oo < 8; ++oo)
#pragma unroll
    for (int p = 0; p < 4; ++p) acc[oo][p] = 0.f;

  stage_phase(ys, &lds[0][0], 0, b, i0, j0, k0, wv, lane);
  for (int ph = 0; ph < 12; ++ph) {
    const float* cur = &lds[ph & 1][0];
    if (ph < 11) {
      stage_phase(ys, &lds[(ph + 1) & 1][0], ph + 1, b, i0, j0, k0, wv, lane);
      // keep next phase's 32 loads in flight; wait out current phase's 32
      asm volatile("s_waitcnt vmcnt(32)" ::: "memory");
    } else {
      asm volatile("s_waitcnt vmcnt(0)" ::: "memory");
    }
    __builtin_amdgcn_s_barrier();
    compute_phase(w + ph*32 + og*8*384, cur, phase_cb(ph), storA, storB, acc);
    asm volatile("" ::: "memory");
    __builtin_amdgcn_s_barrier();     // protect buffer reuse next iteration
  }

  // epilogue: +bias, write out (dwordx4 over 4 consecutive k), fused BN stats
  const int o0 = og*8;
  const int gpos0 = (i0 + di)*1024 + (j0 + dj)*32 + (k0 + 4*u);
  float s1[8], s2[8];
#pragma unroll
  for (int oo = 0; oo < 8; ++oo) {
    const float bias = cb[o0 + oo];
    float4 v;
    v.x = acc[oo][0] + bias; v.y = acc[oo][1] + bias;
    v.z = acc[oo][2] + bias; v.w = acc[oo][3] + bias;
    *(float4*)(out + (((size_t)(b*COUT + o0 + oo)) << 15) + gpos0) = v;
    s1[oo] = (v.x + v.y) + (v.z + v.w);
    s2[oo] = (v.x*v.x + v.y*v.y) + (v.z*v.z + v.w*v.w);
  }
#pragma unroll
  for (int off = 32; off > 0; off >>= 1) {
#pragma unroll
    for (int oo = 0; oo < 8; ++oo) {
      s1[oo] += __shfl_down(s1[oo], off, 64);
      s2[oo] += __shfl_down(s2[oo], off, 64);
    }
  }
  if (lane == 0) {
    float* sh = stats + (bid & 7)*64;   // 8 shadow copies spread contention
#pragma unroll
    for (int oo = 0; oo < 8; ++oo) {
      atomicAdd(&sh[o0 + oo],      s1[oo]);
      atomicAdd(&sh[32 + o0 + oo], s2[oo]);
    }
  }
}

__global__ __launch_bounds__(256, 4) void k_norm(
    float* __restrict__ out, const float* __restrict__ stats,
    const float* __restrict__ gamma, const float* __restrict__ beta)
{
  const int row = blockIdx.x >> 2, quad = blockIdx.x & 3;   // row = b*32+o
  const int o   = row & 31;
  const int tid = threadIdx.x;
  float sum = 0.f, ssq = 0.f;
#pragma unroll
  for (int s = 0; s < 8; ++s) {
    sum += stats[s*64 + o];
    ssq += stats[s*64 + 32 + o];
  }
  const float invN = 1.0f / 131072.0f;
  const float mean = sum * invN;
  const float var  = ssq * invN - mean*mean;
  const float inv  = rsqrtf(var + 1e-5f);
  const float sc   = gamma[o] * inv;
  const float sh   = beta[o] - mean * sc;
  float* p = out + (((size_t)row) << 15) + quad * 8192;
#pragma unroll
  for (int it = 0; it < 8; ++it) {
    float4 v = *(const float4*)(p + it*1024 + tid*4);
    v.x = __builtin_fmaf(v.x, sc, sh);
    v.y = __builtin_fmaf(v.y, sc, sh);
    v.z = __builtin_fmaf(v.z, sc, sh);
    v.w = __builtin_fmaf(v.w, sc, sh);
    *(float4*)(p + it*1024 + tid*4) = v;
  }
}

extern "C" void kernel_launch(void* const* d_in, const int* in_sizes, int n_in,
                              void* d_out, int out_size, void* d_ws, size_t ws_size,
                              hipStream_t stream)
{
  const float* ys    = (const float*)d_in[0];
  const float* w     = (const float*)d_in[1];
  const float* cb    = (const float*)d_in[2];
  const float* gamma = (const float*)d_in[3];
  const float* beta  = (const float*)d_in[4];
  float* out   = (float*)d_out;
  float* stats = (float*)d_ws;    // 8 shadows x 64 floats

  hipMemsetAsync(stats, 0, 8*64*sizeof(float), stream);
  hipLaunchKernelGGL(k_fused, dim3(256), dim3(512), 0, stream, ys, w, cb, out, stats);
  hipLaunchKernelGGL(k_norm,  dim3(512), dim3(256), 0, stream, out, stats, gamma, beta);
}